// Round 2
// baseline (224.346 us; speedup 1.0000x reference)
//
#include <hip/hip_runtime.h>

#define N_FEATURES 4096
#define N_GROUPS   1024
#define BATCH      8192

// Fully fused: out[b] = dot(x[b,:], coeff) where
//   coeff[f] = sum_{i: flat_idx[i]==f} w_flat[i] * diag_w[seg_ids[i]] * dense_W[seg_ids[i]]
//
// Every block redundantly builds the 16 KB coeff table in its own LDS
// (5115 entries; index arrays are L2-resident after first touch), then
// streams 4 rows of x against LDS coeff. This removes the serial
// 1-block build kernel (~8-10 us, 255 idle CUs), one launch gap, and
// the global coeff round-trip.
//
// Occupancy: 256 thr (4 waves) + 16 KB LDS -> 8 blocks/CU = 32 waves/CU;
// grid 2048 = 8 blocks/CU * 256 CUs: the whole grid is co-resident, so
// the redundant build happens once, concurrently, everywhere (~3-4 us),
// then all blocks stream x at the HBM floor.
__global__ __launch_bounds__(256) void fused_kernel(
    const float* __restrict__ x,
    const int*   __restrict__ flat_idx,
    const int*   __restrict__ seg_ids,
    const float* __restrict__ w_flat,
    const float* __restrict__ diag_w,
    const float* __restrict__ dense_W,
    float* __restrict__ out,
    int total)
{
    __shared__ float s_coeff[N_FEATURES];

    // ---- Phase 1: build coeff in LDS (redundant per block; ~20 entries/thread)
    for (int i = threadIdx.x; i < N_FEATURES; i += 256) s_coeff[i] = 0.0f;
    __syncthreads();
    for (int i = threadIdx.x; i < total; i += 256) {
        const int g = seg_ids[i];
        atomicAdd(&s_coeff[flat_idx[i]], w_flat[i] * diag_w[g] * dense_W[g]);
    }
    __syncthreads();

    // ---- Phase 2: one wave per row, 64 lanes x 16 float4 = 4096 floats.
    // x loads coalesced (1 KiB/wave/instr); coeff via lane-contiguous
    // ds_read_b128 (conflict-free); wave-only shuffle reduce, no LDS tail.
    const int wid  = threadIdx.x >> 6;            // wave id: 0..3
    const int lane = threadIdx.x & 63;
    const int row  = (blockIdx.x << 2) | wid;

    const float4* __restrict__ xr = (const float4*)(x + (size_t)row * N_FEATURES);
    const float4* __restrict__ c4 = (const float4*)s_coeff;

    float acc = 0.0f;
#pragma unroll
    for (int k = 0; k < 16; ++k) {
        const int i = (k << 6) | lane;
        const float4 xv = xr[i];
        const float4 cv = c4[i];
        acc += xv.x * cv.x + xv.y * cv.y + xv.z * cv.z + xv.w * cv.w;
    }

#pragma unroll
    for (int off = 32; off > 0; off >>= 1)
        acc += __shfl_down(acc, off, 64);

    if (lane == 0) out[row] = acc;
}

extern "C" void kernel_launch(void* const* d_in, const int* in_sizes, int n_in,
                              void* d_out, int out_size, void* d_ws, size_t ws_size,
                              hipStream_t stream) {
    const float* x        = (const float*)d_in[0];  // [BATCH, N_FEATURES]
    const int*   flat_idx = (const int*)d_in[1];    // [total]
    const int*   seg_ids  = (const int*)d_in[2];    // [total]
    const float* w_flat   = (const float*)d_in[3];  // [total]
    const float* diag_w   = (const float*)d_in[4];  // [N_GROUPS]
    const float* dense_W  = (const float*)d_in[5];  // [N_GROUPS]
    float* out = (float*)d_out;                     // [BATCH] (shape [BATCH,1])
    const int total = in_sizes[1];

    fused_kernel<<<BATCH / 4, 256, 0, stream>>>(x, flat_idx, seg_ids, w_flat,
                                                diag_w, dense_W, out, total);
}

// Round 3
// 208.279 us; speedup vs baseline: 1.0771x; 1.0771x over previous
//
#include <hip/hip_runtime.h>

#define N_FEATURES 4096
#define N_GROUPS   1024
#define BATCH      8192

// Kernel 1: coeff[f] = sum_{i: flat_idx[i]==f} w_flat[i]*diag_w[seg_ids[i]]*dense_W[seg_ids[i]]
// Single block, 1024 threads. Fixed-trip predicated unroll (total=5115 <= 5*1024)
// lets all index/gather loads issue up front instead of serializing behind the
// non-unrollable runtime-bound loop; LDS atomics then drain with latency hidden.
__global__ __launch_bounds__(1024) void build_coeff_kernel(
    const int* __restrict__ flat_idx,
    const int* __restrict__ seg_ids,
    const float* __restrict__ w_flat,
    const float* __restrict__ diag_w,
    const float* __restrict__ dense_W,
    float* __restrict__ coeff,
    int total)
{
    __shared__ float s_coeff[N_FEATURES];
    for (int i = threadIdx.x; i < N_FEATURES; i += 1024) s_coeff[i] = 0.0f;
    __syncthreads();

#pragma unroll
    for (int k = 0; k < 5; ++k) {
        const int i = k * 1024 + (int)threadIdx.x;
        const bool valid = (i < total);
        const int  idx = valid ? flat_idx[i] : 0;
        const int  g   = valid ? seg_ids[i]  : 0;
        const float wv = valid ? w_flat[i]   : 0.0f;
        const float c  = wv * diag_w[g] * dense_W[g];
        if (valid) atomicAdd(&s_coeff[idx], c);
    }
    // robustness tail (not entered when total <= 5120)
    for (int i = 5 * 1024 + (int)threadIdx.x; i < total; i += 1024) {
        const int g = seg_ids[i];
        atomicAdd(&s_coeff[flat_idx[i]], w_flat[i] * diag_w[g] * dense_W[g]);
    }
    __syncthreads();
    for (int i = threadIdx.x; i < N_FEATURES; i += 1024) coeff[i] = s_coeff[i];
}

// Kernel 2: out[b] = dot(x[b,:], coeff), persistent-wave form.
// - Each wave preloads ALL of coeff into 16 float4 regs (64 VGPR/lane;
//   lane l holds coeff4[k*64+l], matching the x access pattern exactly).
//   => ZERO coeff memory traffic during row streaming.
// - Each wave owns 4 rows, processed as 2 interleaved pairs: 32 independent
//   x-loads in flight per pass, two acc chains -> deep MLP, few wave tails.
// - Grid 512 blocks (2/CU, 8 waves/CU): few, long-lived waves; per-wave MLP
//   (32 x 16 B/lane = 32 KB/wave outstanding) covers HBM latency many times over.
__global__ __launch_bounds__(256) void gemv_kernel(
    const float* __restrict__ x,
    const float* __restrict__ coeff,
    float* __restrict__ out)
{
    const int lane = threadIdx.x & 63;
    const int wid  = threadIdx.x >> 6;
    const int wave = (blockIdx.x << 2) | wid;   // 0..2047
    const int row0 = wave << 2;                 // 4 rows per wave

    const float4* __restrict__ c4 = (const float4*)coeff;
    float4 c[16];
#pragma unroll
    for (int k = 0; k < 16; ++k) c[k] = c4[(k << 6) | lane];

#pragma unroll
    for (int p = 0; p < 2; ++p) {
        const int rA = row0 + (p << 1);
        const int rB = rA + 1;
        const float4* __restrict__ xA = (const float4*)(x + (size_t)rA * N_FEATURES);
        const float4* __restrict__ xB = (const float4*)(x + (size_t)rB * N_FEATURES);

        float accA = 0.0f, accB = 0.0f;
#pragma unroll
        for (int k = 0; k < 16; ++k) {
            const int i = (k << 6) | lane;
            const float4 a = xA[i];
            const float4 b = xB[i];
            accA += a.x * c[k].x + a.y * c[k].y + a.z * c[k].z + a.w * c[k].w;
            accB += b.x * c[k].x + b.y * c[k].y + b.z * c[k].z + b.w * c[k].w;
        }

#pragma unroll
        for (int off = 32; off > 0; off >>= 1) {
            accA += __shfl_down(accA, off, 64);
            accB += __shfl_down(accB, off, 64);
        }
        if (lane == 0) {
            out[rA] = accA;
            out[rB] = accB;
        }
    }
}

extern "C" void kernel_launch(void* const* d_in, const int* in_sizes, int n_in,
                              void* d_out, int out_size, void* d_ws, size_t ws_size,
                              hipStream_t stream) {
    const float* x        = (const float*)d_in[0];  // [BATCH, N_FEATURES]
    const int*   flat_idx = (const int*)d_in[1];    // [total]
    const int*   seg_ids  = (const int*)d_in[2];    // [total]
    const float* w_flat   = (const float*)d_in[3];  // [total]
    const float* diag_w   = (const float*)d_in[4];  // [N_GROUPS]
    const float* dense_W  = (const float*)d_in[5];  // [N_GROUPS]
    float* out = (float*)d_out;                     // [BATCH] (shape [BATCH,1])
    const int total = in_sizes[1];

    float* coeff = (float*)d_ws;  // N_FEATURES floats

    build_coeff_kernel<<<1, 1024, 0, stream>>>(flat_idx, seg_ids, w_flat,
                                               diag_w, dense_W, coeff, total);
    gemv_kernel<<<512, 256, 0, stream>>>(x, coeff, out);
}

// Round 6
// 195.947 us; speedup vs baseline: 1.1449x; 1.0629x over previous
//
#include <hip/hip_runtime.h>

#define N_FEATURES 4096
#define N_GROUPS   1024
#define BATCH      8192

typedef float f32x4 __attribute__((ext_vector_type(4)));  // native clang vector:
// __builtin_nontemporal_load accepts this (HIP_vector_type float4 is a struct and is rejected).

// Kernel 1: coeff[f] = sum_{i: flat_idx[i]==f} w_flat[i]*diag_w[seg_ids[i]]*dense_W[seg_ids[i]]
// Single block, 1024 threads, fixed-trip predicated unroll (total=5115 <= 5*1024):
// all gather loads issue up front, LDS atomics drain with latency hidden.
__global__ __launch_bounds__(1024) void build_coeff_kernel(
    const int* __restrict__ flat_idx,
    const int* __restrict__ seg_ids,
    const float* __restrict__ w_flat,
    const float* __restrict__ diag_w,
    const float* __restrict__ dense_W,
    float* __restrict__ coeff,
    int total)
{
    __shared__ float s_coeff[N_FEATURES];
    for (int i = threadIdx.x; i < N_FEATURES; i += 1024) s_coeff[i] = 0.0f;
    __syncthreads();

#pragma unroll
    for (int k = 0; k < 5; ++k) {
        const int i = k * 1024 + (int)threadIdx.x;
        const bool valid = (i < total);
        const int  idx = valid ? flat_idx[i] : 0;
        const int  g   = valid ? seg_ids[i]  : 0;
        const float wv = valid ? w_flat[i]   : 0.0f;
        const float c  = wv * diag_w[g] * dense_W[g];
        if (valid) atomicAdd(&s_coeff[idx], c);
    }
    for (int i = 5 * 1024 + (int)threadIdx.x; i < total; i += 1024) {  // robustness tail
        const int g = seg_ids[i];
        atomicAdd(&s_coeff[flat_idx[i]], w_flat[i] * diag_w[g] * dense_W[g]);
    }
    __syncthreads();
    for (int i = threadIdx.x; i < N_FEATURES; i += 1024) coeff[i] = s_coeff[i];
}

// Kernel 2: out[b] = dot(x[b,:], coeff). Round-1 structure (equal-best):
// one wave per row, 64 lanes x 16 float4, wave-only shuffle reduce.
// CHANGE UNDER TEST: x is loaded NONTEMPORAL (nt bit -> no L2/L3 allocation).
// x is 134 MB of strictly streaming, never-reused data; post-poison L3 is full,
// so every normal miss pays the L3 allocate/evict path and L3 "hits" serve at
// well below HBM stream rate (round-2 evidence: FETCH=66MB for 134MB read,
// 0.85 TB/s on the miss half). coeff stays cached (reused by all 2048 blocks).
__global__ __launch_bounds__(256) void gemv_kernel(
    const float* __restrict__ x,
    const float* __restrict__ coeff,
    float* __restrict__ out)
{
    const int wid  = threadIdx.x >> 6;                 // wave id in block: 0..3
    const int lane = threadIdx.x & 63;
    const int row  = (blockIdx.x << 2) | wid;          // one row per wave

    const f32x4* __restrict__ xr = (const f32x4*)(x + (size_t)row * N_FEATURES);
    const f32x4* __restrict__ c4 = (const f32x4*)coeff;

    float acc = 0.0f;
#pragma unroll
    for (int k = 0; k < 16; ++k) {
        const int i = (k << 6) | lane;                 // coalesced 1 KiB/wave/instr
        const f32x4 xv = __builtin_nontemporal_load(&xr[i]);
        const f32x4 cv = c4[i];                        // cached: 16 KB, reused everywhere
        acc += xv.x * cv.x + xv.y * cv.y + xv.z * cv.z + xv.w * cv.w;
    }

#pragma unroll
    for (int off = 32; off > 0; off >>= 1)
        acc += __shfl_down(acc, off, 64);

    if (lane == 0) out[row] = acc;
}

extern "C" void kernel_launch(void* const* d_in, const int* in_sizes, int n_in,
                              void* d_out, int out_size, void* d_ws, size_t ws_size,
                              hipStream_t stream) {
    const float* x        = (const float*)d_in[0];  // [BATCH, N_FEATURES]
    const int*   flat_idx = (const int*)d_in[1];    // [total]
    const int*   seg_ids  = (const int*)d_in[2];    // [total]
    const float* w_flat   = (const float*)d_in[3];  // [total]
    const float* diag_w   = (const float*)d_in[4];  // [N_GROUPS]
    const float* dense_W  = (const float*)d_in[5];  // [N_GROUPS]
    float* out = (float*)d_out;                     // [BATCH] (shape [BATCH,1])
    const int total = in_sizes[1];

    float* coeff = (float*)d_ws;  // N_FEATURES floats

    build_coeff_kernel<<<1, 1024, 0, stream>>>(flat_idx, seg_ids, w_flat,
                                               diag_w, dense_W, coeff, total);
    gemv_kernel<<<BATCH / 4, 256, 0, stream>>>(x, coeff, out);
}